// Round 6
// baseline (123.855 us; speedup 1.0000x reference)
//
#include <hip/hip_runtime.h>
#include <hip/hip_bf16.h>

// LearnedPairConnect: B=4, N=512, D=48. Output FP32.
// out[i] = sum_j softmax_j(||P_ij||) * P_ij, P = MLP3(concat(x_i,x_j)), j<=i.
// Layer-1 linear split: U = x@W1_top + b1, V = x@W1_bot (uv_kernel).
// R6: per-wave flash softmax (2 barriers/chunk, no sNrm), W3 frags + U in regs,
// W2 in LDS, tail-wave gating, LDS 32512 B -> 5 blocks/CU via launch_bounds(256,5).

constexpr int BATCH = 4;
constexpr int SEQ   = 512;
constexpr int DIM   = 48;
constexpr int DIM2  = 96;
constexpr int CH    = 64;

constexpr int AW  = 104;  // sA / sW2T row stride (shorts): 16B-aligned, 2-way-max banks
constexpr int HW  = 72;   // sH row stride (shorts): 16B-aligned, 2-way-max banks

typedef short short8v __attribute__((ext_vector_type(8)));
typedef float float4v __attribute__((ext_vector_type(4)));
typedef unsigned int uint2v __attribute__((ext_vector_type(2)));
typedef unsigned int uint4v __attribute__((ext_vector_type(4)));

#define MFMA16(a, b, c) __builtin_amdgcn_mfma_f32_16x16x32_bf16(a, b, c, 0, 0, 0)

// Minimal tanh-gelu: gelu(x) = x * (1 - 1/(1 + 2^(x*(c1 + c2*x^2)))).
// c1 = 2*log2(e)*sqrt(2/pi), c2 = c1*0.044715. |err vs exact gelu| <= ~1.5e-4.
__device__ __forceinline__ float gelu_tanh(float x) {
    float u = x * x;
    float q = fmaf(0.10294537f, u, 2.3022077f);
    float e = __builtin_amdgcn_exp2f(x * q);
    float r = __builtin_amdgcn_rcpf(e + 1.0f);
    return fmaf(-x, r, x);
}
__device__ __forceinline__ short f2bf1(float v) {   // bf16 round-half-up
    return (short)((__float_as_uint(v) + 0x8000u) >> 16);
}
__device__ __forceinline__ unsigned pack_bf16x2(float a, float b) {
    unsigned ua = __float_as_uint(a) + 0x8000u;
    unsigned ub = __float_as_uint(b) + 0x8000u;
    return __builtin_amdgcn_perm(ub, ua, 0x07060302u);
}
constexpr float LOG2E = 1.4426950408889634f;

// ---------------- Kernel 1: U = x@W1[:48,:] + b1 ; V = x@W1[48:,:] ----------------
__global__ __launch_bounds__(192) void uv_kernel(
    const float* __restrict__ x, const float* __restrict__ W1,
    const float* __restrict__ b1, float* __restrict__ U, float* __restrict__ V)
{
    __shared__ float sxT[DIM * 4];            // [m][r]
    const int t = threadIdx.x;
    const int row0 = blockIdx.x * 4;
    if (t < DIM * 4) {
        int r = t / DIM, m = t - r * DIM;
        sxT[m * 4 + r] = x[(row0 + r) * DIM + m];
    }
    __syncthreads();
    const bool isU = (t < DIM2);
    const int  k   = isU ? t : (t - DIM2);
    const float* Wcol = W1 + (isU ? 0 : DIM * DIM2) + k;
    float binit = isU ? b1[k] : 0.0f;
    float a0 = binit, a1 = binit, a2 = binit, a3 = binit;
    #pragma unroll 8
    for (int m = 0; m < DIM; ++m) {
        float wv = Wcol[m * DIM2];
        const float4 xa = *(const float4*)&sxT[m * 4];
        a0 = fmaf(wv, xa.x, a0); a1 = fmaf(wv, xa.y, a1);
        a2 = fmaf(wv, xa.z, a2); a3 = fmaf(wv, xa.w, a3);
    }
    float* dst = isU ? U : V;
    dst[(row0 + 0) * DIM2 + k] = a0; dst[(row0 + 1) * DIM2 + k] = a1;
    dst[(row0 + 2) * DIM2 + k] = a2; dst[(row0 + 3) * DIM2 + k] = a3;
}

// ------------- Kernel 2: MFMA pair-MLP, per-wave flash softmax, 2 barriers -------------
__global__ __launch_bounds__(256, 5) void pair_kernel(
    const float* __restrict__ U, const float* __restrict__ V,
    const float* __restrict__ W2, const float* __restrict__ b2,
    const float* __restrict__ W3, const float* __restrict__ b3,
    float* __restrict__ out)
{
    // sA: 13312 B | sW2T: 9984 B | sH (also W3T staging): 9216 B  => 32512 B total
    __shared__ __align__(16) char smem[32512];
    short* sA   = (short*)smem;                    // CH x AW
    short* sW2T = (short*)(smem + 13312);          // DIM x AW (persistent)
    short* sH   = (short*)(smem + 23296);          // CH x HW (k-pad 48..63 zeroed)

    const int t   = threadIdx.x;
    const int bid = blockIdx.x;
    const int b   = bid & (BATCH - 1);
    const int i   = (SEQ - 1) - (bid >> 2);        // LPT: big rows first
    const int rowbase = b * SEQ + i;

    const int lane = t & 63;
    const int w    = t >> 6;              // wave id = M-tile
    const int col  = lane & 15;
    const int quad = lane >> 4;
    const int qo   = quad * 8;
    const int m4   = w * 16 + col;        // A-frag row
    const int rbase = w * 16 + quad * 4;  // C-frag row base

    // ---- staging: W2T -> sW2T (persistent), W3T -> sH rows 0..47 (to harvest),
    //      zero sH k-pad (all 64 rows), zero sA (NaN guard for masked tail rows)
    for (int idx = t; idx < DIM2 * DIM; idx += 256) {       // W2 [96][48] -> sW2T[n][k]
        int k = idx / DIM, n = idx - k * DIM;
        sW2T[n * AW + k] = f2bf1(W2[idx]);
    }
    for (int idx = t; idx < DIM * DIM; idx += 256) {        // W3 [48][48] -> sH[n][k]
        int k = idx / DIM, n = idx - k * DIM;
        sH[n * HW + k] = f2bf1(W3[idx]);
    }
    for (int idx = t; idx < CH * 16; idx += 256)            // zero sH k=48..63, 64 rows
        sH[(idx >> 4) * HW + 48 + (idx & 15)] = 0;
    {
        uint4v z = {0u, 0u, 0u, 0u};
        for (int idx = t; idx < (CH * AW * 2) / 16; idx += 256)
            ((uint4v*)sA)[idx] = z;
    }
    // uu: this thread's U slice, registers (6 float4)
    const int pr = t >> 2;             // A-pack row 0..63 (wave-aligned: wave w -> w*16..+15)
    const int pq = t & 3;
    float4 uu[6];
    #pragma unroll
    for (int k = 0; k < 6; ++k) uu[k] = *(const float4*)&U[rowbase * DIM2 + (pq + 4 * k) * 4];
    __syncthreads();

    // ---- loop-invariant register fragments: W3 B-operands (reads k 0..63 incl pad) ----
    const short* w3b = sH + col * HW + qo;
    const short8v w300 = *(const short8v*)(w3b + 0);
    const short8v w301 = *(const short8v*)(w3b + 32);
    const short8v w310 = *(const short8v*)(w3b + 16*HW + 0);
    const short8v w311 = *(const short8v*)(w3b + 16*HW + 32);
    const short8v w320 = *(const short8v*)(w3b + 32*HW + 0);
    const short8v w321 = *(const short8v*)(w3b + 32*HW + 32);
    const float bb20 = b2[col], bb21 = b2[16 + col], bb22 = b2[32 + col];
    const float bb30 = b3[col], bb31 = b3[16 + col], bb32 = b3[32 + col];
    __syncthreads();   // frags harvested; sH region free

    float acc0 = 0.f, acc1 = 0.f, acc2 = 0.f;   // wave-local weighted sums (own 16 rows)
    float m_run = -1e30f, l_run = 0.0f;          // wave-private flash state

    for (int j0 = 0; j0 <= i; j0 += CH) {
        const int jmax = i - j0;                     // JJ-1
        const bool active = ((w << 4) <= jmax);      // any of this wave's rows valid?

        // ---- A-pack: A = gelu(U_i + V_j) -> bf16 LDS, own 16 rows
        if (active) {
            const float* Vb = V + (b * SEQ + j0 + pr) * DIM2 + pq * 4;
            #pragma unroll
            for (int kk = 0; kk < 6; ++kk) {
                const float4 vv = *(const float4*)(Vb + 16 * kk);
                float g0 = gelu_tanh(uu[kk].x + vv.x);
                float g1 = gelu_tanh(uu[kk].y + vv.y);
                float g2 = gelu_tanh(uu[kk].z + vv.z);
                float g3 = gelu_tanh(uu[kk].w + vv.w);
                uint2v o;
                o.x = pack_bf16x2(g0, g1);
                o.y = pack_bf16x2(g2, g3);
                *(uint2v*)&sA[pr * AW + (pq + 4 * kk) * 4] = o;
            }
        }
        __syncthreads();   // B1: A ready

        // ---- GEMM2: H = gelu(A @ W2 + b2), K=96; W2 B-frags from LDS
        if (active) {
            const short* arow = &sA[m4 * AW + qo];
            short8v a0 = *(const short8v*)(arow + 0);
            short8v a1 = *(const short8v*)(arow + 32);
            short8v a2 = *(const short8v*)(arow + 64);
            const short* w2b = sW2T + col * AW + qo;
            float4v c0 = {0.f,0.f,0.f,0.f}, c1 = c0, c2 = c0;
            c0 = MFMA16(a0, *(const short8v*)(w2b + 0),          c0);
            c0 = MFMA16(a1, *(const short8v*)(w2b + 32),         c0);
            c0 = MFMA16(a2, *(const short8v*)(w2b + 64),         c0);
            c1 = MFMA16(a0, *(const short8v*)(w2b + 16*AW + 0),  c1);
            c1 = MFMA16(a1, *(const short8v*)(w2b + 16*AW + 32), c1);
            c1 = MFMA16(a2, *(const short8v*)(w2b + 16*AW + 64), c1);
            c2 = MFMA16(a0, *(const short8v*)(w2b + 32*AW + 0),  c2);
            c2 = MFMA16(a1, *(const short8v*)(w2b + 32*AW + 32), c2);
            c2 = MFMA16(a2, *(const short8v*)(w2b + 32*AW + 64), c2);
            #pragma unroll
            for (int r = 0; r < 4; ++r) {
                sH[(rbase + r) * HW +  0 + col] = f2bf1(gelu_tanh(c0[r] + bb20));
                sH[(rbase + r) * HW + 16 + col] = f2bf1(gelu_tanh(c1[r] + bb21));
                sH[(rbase + r) * HW + 32 + col] = f2bf1(gelu_tanh(c2[r] + bb22));
            }
        }
        __syncthreads();   // B2: H ready

        // ---- GEMM3 + per-wave flash update (no barrier needed after)
        if (active) {
            const short* hrw = &sH[m4 * HW + qo];
            short8v a0 = *(const short8v*)(hrw + 0);
            short8v a1 = *(const short8v*)(hrw + 32);
            float4v c0 = {0.f,0.f,0.f,0.f}, c1 = c0, c2 = c0;
            c0 = MFMA16(a0, w300, c0); c0 = MFMA16(a1, w301, c0);
            c1 = MFMA16(a0, w310, c1); c1 = MFMA16(a1, w311, c1);
            c2 = MFMA16(a0, w320, c2); c2 = MFMA16(a1, w321, c2);
            float4v p0, p1, p2;
            float vr[4];
            #pragma unroll
            for (int r = 0; r < 4; ++r) {
                p0[r] = c0[r] + bb30; p1[r] = c1[r] + bb31; p2[r] = c2[r] + bb32;
                float ss = p0[r]*p0[r] + p1[r]*p1[r] + p2[r]*p2[r];
                ss += __shfl_xor(ss, 1);
                ss += __shfl_xor(ss, 2);
                ss += __shfl_xor(ss, 4);
                ss += __shfl_xor(ss, 8);   // all 16 lanes of quad now hold full ||P_row||^2
                vr[r] = (rbase + r <= jmax) ? __builtin_amdgcn_sqrtf(ss) : -1e30f;
            }
            float mloc = fmaxf(fmaxf(vr[0], vr[1]), fmaxf(vr[2], vr[3]));
            mloc = fmaxf(mloc, __shfl_xor(mloc, 16));
            mloc = fmaxf(mloc, __shfl_xor(mloc, 32));   // max over wave's 16 rows
            float newm = fmaxf(m_run, mloc);
            float sc = __builtin_amdgcn_exp2f((m_run - newm) * LOG2E);  // 0 on first chunk
            float e0 = __builtin_amdgcn_exp2f((vr[0] - newm) * LOG2E);  // masked rows -> 0
            float e1 = __builtin_amdgcn_exp2f((vr[1] - newm) * LOG2E);
            float e2 = __builtin_amdgcn_exp2f((vr[2] - newm) * LOG2E);
            float e3 = __builtin_amdgcn_exp2f((vr[3] - newm) * LOG2E);
            float s = (e0 + e1) + (e2 + e3);
            s += __shfl_xor(s, 16);
            s += __shfl_xor(s, 32);        // sum over wave's 16 rows
            l_run = fmaf(l_run, sc, s);
            m_run = newm;
            acc0 *= sc; acc1 *= sc; acc2 *= sc;
            acc0 = fmaf(e0, p0[0], acc0); acc1 = fmaf(e0, p1[0], acc1); acc2 = fmaf(e0, p2[0], acc2);
            acc0 = fmaf(e1, p0[1], acc0); acc1 = fmaf(e1, p1[1], acc1); acc2 = fmaf(e1, p2[1], acc2);
            acc0 = fmaf(e2, p0[2], acc0); acc1 = fmaf(e2, p1[2], acc1); acc2 = fmaf(e2, p2[2], acc2);
            acc0 = fmaf(e3, p0[3], acc0); acc1 = fmaf(e3, p1[3], acc1); acc2 = fmaf(e3, p2[3], acc2);
        }
    }

    // ---- cross-wave flash merge: out = sum_w f_w*acc_w / sum_w f_w*l_w, f_w=e^(m_w-M)
    acc0 += __shfl_xor(acc0, 16); acc0 += __shfl_xor(acc0, 32);
    acc1 += __shfl_xor(acc1, 16); acc1 += __shfl_xor(acc1, 32);
    acc2 += __shfl_xor(acc2, 16); acc2 += __shfl_xor(acc2, 32);
    float* red = (float*)smem;    // reuse sA region: 4 waves x 64 floats
    __syncthreads();
    if (lane < 16) {
        red[w * 64 + lane]      = acc0;
        red[w * 64 + 16 + lane] = acc1;
        red[w * 64 + 32 + lane] = acc2;
    }
    if (lane == 0) { red[w * 64 + 48] = m_run; red[w * 64 + 49] = l_run; }
    __syncthreads();
    if (t < DIM) {
        float mm0 = red[48],       mm1 = red[64 + 48];
        float mm2 = red[128 + 48], mm3 = red[192 + 48];
        float M = fmaxf(fmaxf(mm0, mm1), fmaxf(mm2, mm3));
        float f0 = __builtin_amdgcn_exp2f((mm0 - M) * LOG2E);
        float f1 = __builtin_amdgcn_exp2f((mm1 - M) * LOG2E);
        float f2 = __builtin_amdgcn_exp2f((mm2 - M) * LOG2E);
        float f3 = __builtin_amdgcn_exp2f((mm3 - M) * LOG2E);
        float num = f0 * red[t] + f1 * red[64 + t] + f2 * red[128 + t] + f3 * red[192 + t];
        float den = f0 * red[49] + f1 * red[64 + 49] + f2 * red[128 + 49] + f3 * red[192 + 49];
        out[rowbase * DIM + t] = num / den;
    }
}

extern "C" void kernel_launch(void* const* d_in, const int* in_sizes, int n_in,
                              void* d_out, int out_size, void* d_ws, size_t ws_size,
                              hipStream_t stream) {
    const float* x  = (const float*)d_in[0];
    const float* W1 = (const float*)d_in[1];
    const float* b1 = (const float*)d_in[2];
    const float* W2 = (const float*)d_in[3];
    const float* b2 = (const float*)d_in[4];
    const float* W3 = (const float*)d_in[5];
    const float* b3 = (const float*)d_in[6];
    float* out = (float*)d_out;

    float* U = (float*)d_ws;                       // [B*N, 96]
    float* V = U + BATCH * SEQ * DIM2;             // [B*N, 96]

    uv_kernel<<<BATCH * SEQ / 4, 192, 0, stream>>>(x, W1, b1, U, V);
    pair_kernel<<<BATCH * SEQ, 256, 0, stream>>>(U, V, W2, b2, W3, b3, out);
}

// Round 7
// 107.542 us; speedup vs baseline: 1.1517x; 1.1517x over previous
//
#include <hip/hip_runtime.h>
#include <hip/hip_bf16.h>

// LearnedPairConnect: B=4, N=512, D=48. Output FP32.
// out[i] = sum_j softmax_j(||P_ij||) * P_ij, P = MLP3(concat(x_i,x_j)), j<=i.
// Layer-1 linear split: U = x@W1_top + b1, V = x@W1_bot (uv_kernel).
// R7: BARRIER-FREE K-loop. All LDS regions in the loop are wave-private
// (wave w owns rows 16w..16w+15 of sA and sH); within-wave ds_write->ds_read
// is ordered by the in-order DS pipe. Per-wave trip count (j0+16w <= i),
// per-wave flash softmax, one merge barrier at the end.
// W2/W3 MFMA B-frags + biases hoisted to AGPRs/SGPRs; launch_bounds(256,4)
// (R6 lesson: (256,5) caps regs at ~102 -> scratch spills, 24 MB HBM traffic).

constexpr int BATCH = 4;
constexpr int SEQ   = 512;
constexpr int DIM   = 48;
constexpr int DIM2  = 96;
constexpr int CH    = 64;

constexpr int AW  = 104;  // sA row stride (shorts): 16B-aligned, 2-way-max banks
constexpr int HW  = 72;   // sH row stride (shorts): 16B-aligned, 2-way-max banks

typedef short short8v __attribute__((ext_vector_type(8)));
typedef float float4v __attribute__((ext_vector_type(4)));
typedef unsigned int uint2v __attribute__((ext_vector_type(2)));

#define MFMA16(a, b, c) __builtin_amdgcn_mfma_f32_16x16x32_bf16(a, b, c, 0, 0, 0)

// Minimal tanh-gelu: gelu(x) = x * (1 - 1/(1 + 2^(x*(c1 + c2*x^2)))).
// c1 = 2*log2(e)*sqrt(2/pi), c2 = c1*0.044715. |err vs exact gelu| <= ~1.5e-4.
__device__ __forceinline__ float gelu_tanh(float x) {
    float u = x * x;
    float q = fmaf(0.10294537f, u, 2.3022077f);
    float e = __builtin_amdgcn_exp2f(x * q);
    float r = __builtin_amdgcn_rcpf(e + 1.0f);
    return fmaf(-x, r, x);
}
__device__ __forceinline__ short f2bf1(float v) {   // bf16 round-half-up
    return (short)((__float_as_uint(v) + 0x8000u) >> 16);
}
__device__ __forceinline__ unsigned pack_bf16x2(float a, float b) {
    unsigned ua = __float_as_uint(a) + 0x8000u;
    unsigned ub = __float_as_uint(b) + 0x8000u;
    return __builtin_amdgcn_perm(ub, ua, 0x07060302u);
}
constexpr float LOG2E = 1.4426950408889634f;

// ---------------- Kernel 1: U = x@W1[:48,:] + b1 ; V = x@W1[48:,:] ----------------
__global__ __launch_bounds__(192) void uv_kernel(
    const float* __restrict__ x, const float* __restrict__ W1,
    const float* __restrict__ b1, float* __restrict__ U, float* __restrict__ V)
{
    __shared__ float sxT[DIM * 4];            // [m][r]
    const int t = threadIdx.x;
    const int row0 = blockIdx.x * 4;
    if (t < DIM * 4) {
        int r = t / DIM, m = t - r * DIM;
        sxT[m * 4 + r] = x[(row0 + r) * DIM + m];
    }
    __syncthreads();
    const bool isU = (t < DIM2);
    const int  k   = isU ? t : (t - DIM2);
    const float* Wcol = W1 + (isU ? 0 : DIM * DIM2) + k;
    float binit = isU ? b1[k] : 0.0f;
    float a0 = binit, a1 = binit, a2 = binit, a3 = binit;
    #pragma unroll 8
    for (int m = 0; m < DIM; ++m) {
        float wv = Wcol[m * DIM2];
        const float4 xa = *(const float4*)&sxT[m * 4];
        a0 = fmaf(wv, xa.x, a0); a1 = fmaf(wv, xa.y, a1);
        a2 = fmaf(wv, xa.z, a2); a3 = fmaf(wv, xa.w, a3);
    }
    float* dst = isU ? U : V;
    dst[(row0 + 0) * DIM2 + k] = a0; dst[(row0 + 1) * DIM2 + k] = a1;
    dst[(row0 + 2) * DIM2 + k] = a2; dst[(row0 + 3) * DIM2 + k] = a3;
}

// -------- Kernel 2: MFMA pair-MLP, barrier-free K-loop, per-wave flash softmax --------
__global__ __launch_bounds__(256, 4) void pair_kernel(
    const float* __restrict__ U, const float* __restrict__ V,
    const float* __restrict__ W2, const float* __restrict__ b2,
    const float* __restrict__ W3, const float* __restrict__ b3,
    float* __restrict__ out)
{
    // region1 (13312 B): W2T staging -> per-wave sA rows -> final merge area
    // region2 ( 9216 B): W3T staging -> per-wave sH rows (k-pad 48..63 stays zero)
    __shared__ __align__(16) char smem[23296];
    short* sA  = (short*)smem;                 // CH x AW
    short* sH  = (short*)(smem + 13312);       // CH x HW
    float* sUi = (float*)(smem + 22528);       // 96 floats

    const int t   = threadIdx.x;
    const int bid = blockIdx.x;
    const int b   = bid & (BATCH - 1);
    const int i   = (SEQ - 1) - (bid >> 2);    // LPT: big rows first
    const int rowbase = b * SEQ + i;

    const int lane = t & 63;
    const int w    = t >> 6;              // wave id = M-tile (rows 16w..16w+15)
    const int col  = lane & 15;
    const int quad = lane >> 4;
    const int qo   = quad * 8;
    const int m4   = w * 16 + col;        // A-frag row (wave-private)
    const int rbase = w * 16 + quad * 4;  // C-frag row base (wave-private)

    // ---- staging: W2T -> sA region, W3T -> sH rows 0..47, zero sH k-pad ----
    for (int idx = t; idx < DIM2 * DIM; idx += 256) {       // W2 [96][48] -> sA[n][k]
        int k = idx / DIM, n = idx - k * DIM;
        sA[n * AW + k] = f2bf1(W2[idx]);
    }
    for (int idx = t; idx < DIM * DIM; idx += 256) {        // W3 [48][48] -> sH[n][k]
        int k = idx / DIM, n = idx - k * DIM;
        sH[n * HW + k] = f2bf1(W3[idx]);
    }
    for (int idx = t; idx < CH * 16; idx += 256)            // zero sH k=48..63, 64 rows
        sH[(idx >> 4) * HW + 48 + (idx & 15)] = 0;
    if (t < DIM2) sUi[t] = U[rowbase * DIM2 + t];
    __syncthreads();

    // ---- loop-invariant register fragments (B-operands) + biases ----
    const short* w2b = sA + col * AW + qo;
    const short8v w200 = *(const short8v*)(w2b + 0);
    const short8v w201 = *(const short8v*)(w2b + 32);
    const short8v w202 = *(const short8v*)(w2b + 64);
    const short8v w210 = *(const short8v*)(w2b + 16*AW + 0);
    const short8v w211 = *(const short8v*)(w2b + 16*AW + 32);
    const short8v w212 = *(const short8v*)(w2b + 16*AW + 64);
    const short8v w220 = *(const short8v*)(w2b + 32*AW + 0);
    const short8v w221 = *(const short8v*)(w2b + 32*AW + 32);
    const short8v w222 = *(const short8v*)(w2b + 32*AW + 64);
    const short* w3b = sH + col * HW + qo;
    const short8v w300 = *(const short8v*)(w3b + 0);
    const short8v w301 = *(const short8v*)(w3b + 32);
    const short8v w310 = *(const short8v*)(w3b + 16*HW + 0);
    const short8v w311 = *(const short8v*)(w3b + 16*HW + 32);
    const short8v w320 = *(const short8v*)(w3b + 32*HW + 0);
    const short8v w321 = *(const short8v*)(w3b + 32*HW + 32);
    const float bb20 = b2[col], bb21 = b2[16 + col], bb22 = b2[32 + col];
    const float bb30 = b3[col], bb31 = b3[16 + col], bb32 = b3[32 + col];
    __syncthreads();   // frags harvested; sA/sH regions become wave-private

    // A-pack geometry: 4 lanes per row; wave w's 64 lanes cover rows 16w..16w+15
    const int pr = t >> 2;             // row index
    const int pq = t & 3;

    float acc0 = 0.f, acc1 = 0.f, acc2 = 0.f;    // wave-local weighted sums
    float m_run = -1e30f, l_run = 0.0f;           // wave-private flash state

    // per-wave trip count; V index j0+pr <= 448+63 = 511, always in-bounds
    for (int j0 = 0; j0 + (w << 4) <= i; j0 += CH) {
        const int jmax = i - j0;

        // ---- A-pack: A = gelu(U_i + V_j) -> bf16 LDS, own 16 rows
        {
            const float* Vb = V + (b * SEQ + j0 + pr) * DIM2 + pq * 4;
            #pragma unroll
            for (int kk = 0; kk < 6; ++kk) {
                const float4 vv = *(const float4*)(Vb + 16 * kk);
                const float4 uu = *(const float4*)&sUi[(pq + 4 * kk) * 4];
                float g0 = gelu_tanh(uu.x + vv.x);
                float g1 = gelu_tanh(uu.y + vv.y);
                float g2 = gelu_tanh(uu.z + vv.z);
                float g3 = gelu_tanh(uu.w + vv.w);
                uint2v o;
                o.x = pack_bf16x2(g0, g1);
                o.y = pack_bf16x2(g2, g3);
                *(uint2v*)&sA[pr * AW + (pq + 4 * kk) * 4] = o;
            }
        }
        // no barrier: in-order DS pipe orders this wave's writes before its reads

        // ---- GEMM2: H = gelu(A @ W2 + b2), K=96 (reg B-frags), own rows
        {
            const short* arow = &sA[m4 * AW + qo];
            short8v a0 = *(const short8v*)(arow + 0);
            short8v a1 = *(const short8v*)(arow + 32);
            short8v a2 = *(const short8v*)(arow + 64);
            float4v c0 = {0.f,0.f,0.f,0.f}, c1 = c0, c2 = c0;
            c0 = MFMA16(a0, w200, c0); c0 = MFMA16(a1, w201, c0); c0 = MFMA16(a2, w202, c0);
            c1 = MFMA16(a0, w210, c1); c1 = MFMA16(a1, w211, c1); c1 = MFMA16(a2, w212, c1);
            c2 = MFMA16(a0, w220, c2); c2 = MFMA16(a1, w221, c2); c2 = MFMA16(a2, w222, c2);
            #pragma unroll
            for (int r = 0; r < 4; ++r) {
                sH[(rbase + r) * HW +  0 + col] = f2bf1(gelu_tanh(c0[r] + bb20));
                sH[(rbase + r) * HW + 16 + col] = f2bf1(gelu_tanh(c1[r] + bb21));
                sH[(rbase + r) * HW + 32 + col] = f2bf1(gelu_tanh(c2[r] + bb22));
            }
        }
        // no barrier: same-wave rows only

        // ---- GEMM3 + per-wave flash update
        {
            const short* hrw = &sH[m4 * HW + qo];
            short8v a0 = *(const short8v*)(hrw + 0);
            short8v a1 = *(const short8v*)(hrw + 32);
            float4v c0 = {0.f,0.f,0.f,0.f}, c1 = c0, c2 = c0;
            c0 = MFMA16(a0, w300, c0); c0 = MFMA16(a1, w301, c0);
            c1 = MFMA16(a0, w310, c1); c1 = MFMA16(a1, w311, c1);
            c2 = MFMA16(a0, w320, c2); c2 = MFMA16(a1, w321, c2);
            float4v p0, p1, p2;
            float vr[4];
            #pragma unroll
            for (int r = 0; r < 4; ++r) {
                p0[r] = c0[r] + bb30; p1[r] = c1[r] + bb31; p2[r] = c2[r] + bb32;
                float ss = p0[r]*p0[r] + p1[r]*p1[r] + p2[r]*p2[r];
                ss += __shfl_xor(ss, 1);
                ss += __shfl_xor(ss, 2);
                ss += __shfl_xor(ss, 4);
                ss += __shfl_xor(ss, 8);   // full ||P_row||^2 in all 16 lanes of quad
                vr[r] = (rbase + r <= jmax) ? __builtin_amdgcn_sqrtf(ss) : -1e30f;
            }
            float mloc = fmaxf(fmaxf(vr[0], vr[1]), fmaxf(vr[2], vr[3]));
            mloc = fmaxf(mloc, __shfl_xor(mloc, 16));
            mloc = fmaxf(mloc, __shfl_xor(mloc, 32));   // max over wave's 16 rows
            float newm = fmaxf(m_run, mloc);
            float sc = __builtin_amdgcn_exp2f((m_run - newm) * LOG2E);  // 0 on 1st chunk
            float e0 = __builtin_amdgcn_exp2f((vr[0] - newm) * LOG2E);  // masked -> 0
            float e1 = __builtin_amdgcn_exp2f((vr[1] - newm) * LOG2E);
            float e2 = __builtin_amdgcn_exp2f((vr[2] - newm) * LOG2E);
            float e3 = __builtin_amdgcn_exp2f((vr[3] - newm) * LOG2E);
            float s = (e0 + e1) + (e2 + e3);
            s += __shfl_xor(s, 16);
            s += __shfl_xor(s, 32);        // sum over wave's 16 rows
            l_run = fmaf(l_run, sc, s);
            m_run = newm;
            acc0 *= sc; acc1 *= sc; acc2 *= sc;
            acc0 = fmaf(e0, p0[0], acc0); acc1 = fmaf(e0, p1[0], acc1); acc2 = fmaf(e0, p2[0], acc2);
            acc0 = fmaf(e1, p0[1], acc0); acc1 = fmaf(e1, p1[1], acc1); acc2 = fmaf(e1, p2[1], acc2);
            acc0 = fmaf(e2, p0[2], acc0); acc1 = fmaf(e2, p1[2], acc1); acc2 = fmaf(e2, p2[2], acc2);
            acc0 = fmaf(e3, p0[3], acc0); acc1 = fmaf(e3, p1[3], acc1); acc2 = fmaf(e3, p2[3], acc2);
        }
    }

    // ---- cross-wave flash merge: out = sum_w f_w*acc_w / sum_w f_w*l_w ----
    acc0 += __shfl_xor(acc0, 16); acc0 += __shfl_xor(acc0, 32);
    acc1 += __shfl_xor(acc1, 16); acc1 += __shfl_xor(acc1, 32);
    acc2 += __shfl_xor(acc2, 16); acc2 += __shfl_xor(acc2, 32);
    float* red = (float*)smem;    // reuse region1: 4 waves x 64 floats
    __syncthreads();              // all waves done with loop LDS
    if (lane < 16) {
        red[w * 64 + lane]      = acc0;
        red[w * 64 + 16 + lane] = acc1;
        red[w * 64 + 32 + lane] = acc2;
    }
    if (lane == 0) { red[w * 64 + 48] = m_run; red[w * 64 + 49] = l_run; }
    __syncthreads();
    if (t < DIM) {
        float mm0 = red[48],       mm1 = red[64 + 48];
        float mm2 = red[128 + 48], mm3 = red[192 + 48];
        float M = fmaxf(fmaxf(mm0, mm1), fmaxf(mm2, mm3));
        float f0 = __builtin_amdgcn_exp2f((mm0 - M) * LOG2E);  // m=-1e30 (no chunks) -> 0
        float f1 = __builtin_amdgcn_exp2f((mm1 - M) * LOG2E);
        float f2 = __builtin_amdgcn_exp2f((mm2 - M) * LOG2E);
        float f3 = __builtin_amdgcn_exp2f((mm3 - M) * LOG2E);
        float num = f0 * red[t] + f1 * red[64 + t] + f2 * red[128 + t] + f3 * red[192 + t];
        float den = f0 * red[49] + f1 * red[64 + 49] + f2 * red[128 + 49] + f3 * red[192 + 49];
        out[rowbase * DIM + t] = num / den;
    }
}

extern "C" void kernel_launch(void* const* d_in, const int* in_sizes, int n_in,
                              void* d_out, int out_size, void* d_ws, size_t ws_size,
                              hipStream_t stream) {
    const float* x  = (const float*)d_in[0];
    const float* W1 = (const float*)d_in[1];
    const float* b1 = (const float*)d_in[2];
    const float* W2 = (const float*)d_in[3];
    const float* b2 = (const float*)d_in[4];
    const float* W3 = (const float*)d_in[5];
    const float* b3 = (const float*)d_in[6];
    float* out = (float*)d_out;

    float* U = (float*)d_ws;                       // [B*N, 96]
    float* V = U + BATCH * SEQ * DIM2;             // [B*N, 96]

    uv_kernel<<<BATCH * SEQ / 4, 192, 0, stream>>>(x, W1, b1, U, V);
    pair_kernel<<<BATCH * SEQ, 256, 0, stream>>>(U, V, W2, b2, W3, b3, out);
}